// Round 7
// baseline (98.329 us; speedup 1.0000x reference)
//
#include <hip/hip_runtime.h>
#include <math.h>

#define NS 256000
#define N1 512            // FFT over n1: radix 8,8,8
#define N2 500            // FFT over n2: radices 5,5,5,4
#define PI_F 3.14159265358979323846f

typedef float2 cplx;

__device__ __forceinline__ cplx cadd(cplx a, cplx b){ return make_float2(a.x+b.x, a.y+b.y); }
__device__ __forceinline__ cplx csub(cplx a, cplx b){ return make_float2(a.x-b.x, a.y-b.y); }
__device__ __forceinline__ cplx cmul(cplx a, cplx b){ return make_float2(a.x*b.x-a.y*b.y, a.x*b.y+a.y*b.x); }
__device__ __forceinline__ cplx cmulc(cplx a, cplx b){ return make_float2(a.x*b.x+a.y*b.y, a.y*b.x-a.x*b.y); }
__device__ __forceinline__ cplx crotf(cplx v, float ang){
    float sn = __sinf(ang), cs = __cosf(ang);
    return make_float2(v.x*cs - v.y*sn, v.x*sn + v.y*cs);
}
// padded LDS index: +1 word every 16 elements -> <=2-way bank aliasing
__device__ __forceinline__ int PX(int e){ return e + (e>>4); }
// octal digit reversal of 9 bits (involution)
__device__ __forceinline__ int rev8_3(int k){ return ((k&7)<<6) | (k&0x38) | (k>>6); }

#define UPAD 545            // one stride for both 512-pt (PX(511)=542) and 500-pt (PX(499)=530)
#define U_OFF   4096u       // tab at 0 (<=512 cplx), U columns at 4096 + c*UPAD*8
#define EX_OFF  21536u      // phase-specific region
#define SMEM_BYTES 34816

// wave-level LDS fence: wave-private columns, no block barrier needed
#define WFENCE() asm volatile("s_waitcnt lgkmcnt(0)" ::: "memory")
// LDS-only block barrier: does NOT drain vmcnt, so global loads stay in flight
#define LDS_BARRIER() do{ asm volatile("s_waitcnt lgkmcnt(0)" ::: "memory"); __builtin_amdgcn_s_barrier(); }while(0)

template<bool INV>
__device__ __forceinline__ void dft4(const cplx* a, cplx* b){
    cplx t0=cadd(a[0],a[2]), t1=csub(a[0],a[2]), t2=cadd(a[1],a[3]), t3=csub(a[1],a[3]);
    b[0]=cadd(t0,t2); b[2]=csub(t0,t2);
    if(!INV){ b[1]=make_float2(t1.x+t3.y, t1.y-t3.x); b[3]=make_float2(t1.x-t3.y, t1.y+t3.x); }
    else    { b[1]=make_float2(t1.x-t3.y, t1.y+t3.x); b[3]=make_float2(t1.x+t3.y, t1.y-t3.x); }
}

template<bool INV>
__device__ __forceinline__ void dft8(const cplx* a, cplx* b){
    cplx ev[4]={a[0],a[2],a[4],a[6]}, od[4]={a[1],a[3],a[5],a[7]};
    cplx C[4], D[4];
    dft4<INV>(ev, C); dft4<INV>(od, D);
    const float s = 0.70710678118654752f;
    const float sg = INV ? 1.f : -1.f;
    cplx d1 = cmul(D[1], make_float2( s, sg*s));
    cplx d2 = cmul(D[2], make_float2(0.f, sg ));
    cplx d3 = cmul(D[3], make_float2(-s, sg*s));
    b[0]=cadd(C[0],D[0]); b[4]=csub(C[0],D[0]);
    b[1]=cadd(C[1],d1);   b[5]=csub(C[1],d1);
    b[2]=cadd(C[2],d2);   b[6]=csub(C[2],d2);
    b[3]=cadd(C[3],d3);   b[7]=csub(C[3],d3);
}

template<bool INV>
__device__ __forceinline__ void dft5(const cplx* a, cplx* b){
    const float c1=0.30901699437494742f, s1=0.95105651629515357f;
    const float c2=-0.80901699437494745f, s2=0.58778525229247312f;
    const float sg = INV ? 1.f : -1.f;
    cplx W[5];
    W[0]=make_float2(1.f,0.f);
    W[1]=make_float2(c1, sg*s1); W[2]=make_float2(c2, sg*s2);
    W[3]=make_float2(c2,-sg*s2); W[4]=make_float2(c1,-sg*s1);
#pragma unroll
    for(int u=0;u<5;++u){
        cplx acc = a[0];
        int idx = 0;
#pragma unroll
        for(int r=1;r<5;++r){
            idx += u; if(idx >= 5) idx -= 5;
            acc = cadd(acc, cmul(a[r], W[idx]));
        }
        b[u] = acc;
    }
}

// ---- deduplicated stage bodies: ONE copy each in the binary (noinline) ----
// radix-8 stage on a wave-private 512-pt column; runtime sh in {6,3,0} (fwd)
// or {0,3,6} (inv); twiddle stride = (j*t) << (6-sh); tab at LDS offset 0.
template<bool INV>
__device__ __noinline__ void stage8(unsigned uoff, int lane, int sh){
    extern __shared__ char smem[];
    cplx* tab = (cplx*)smem;
    cplx* Uw  = (cplx*)(smem + uoff);
    const int m = 1 << sh;
    const int blk = lane >> sh, j = lane & (m-1);
    const int base = (blk << (sh+3)) + j;
    const int ts = 6 - sh;
    cplx a[8], wt[8];
#pragma unroll
    for(int t=0;t<8;++t) a[t] = Uw[PX(base + (t<<sh))];
#pragma unroll
    for(int t=1;t<8;++t) wt[t] = tab[(j*t) << ts];
    if(INV){
#pragma unroll
        for(int t=1;t<8;++t) a[t] = cmulc(a[t], wt[t]);
    }
    cplx bb[8];
    dft8<INV>(a,bb);
    if(!INV){
#pragma unroll
        for(int t=1;t<8;++t) bb[t] = cmul(bb[t], wt[t]);
    }
#pragma unroll
    for(int t=0;t<8;++t) Uw[PX(base + (t<<sh))] = bb[t];
}

// radix-5 stage on a wave-private 500-pt column; runtime m in {100,20,4} with
// recip = ceil(65536/m) (exact div for beta<128); twiddle stride tmul.
template<bool INV>
__device__ __noinline__ void stage5(unsigned uoff, int lane, int m, unsigned recip, int tmul){
    extern __shared__ char smem[];
    cplx* tab = (cplx*)smem;
    cplx* Uw  = (cplx*)(smem + uoff);
#pragma unroll
    for(int it=0; it<2; ++it){
        int beta = lane + 64*it;
        if(beta < 100){
            int blk = (int)(((unsigned)beta*recip)>>16);
            int j = beta - blk*m;
            int base = blk*(5*m) + j;
            cplx a[5], wt[5];
#pragma unroll
            for(int t=0;t<5;++t) a[t] = Uw[PX(base + m*t)];
#pragma unroll
            for(int t=1;t<5;++t) wt[t] = tab[tmul*j*t];
            if(INV){
#pragma unroll
                for(int t=1;t<5;++t) a[t] = cmulc(a[t], wt[t]);
            }
            cplx bb[5];
            dft5<INV>(a,bb);
            if(!INV){
#pragma unroll
                for(int t=1;t<5;++t) bb[t] = cmul(bb[t], wt[t]);
            }
#pragma unroll
            for(int t=0;t<5;++t) Uw[PX(base + m*t)] = bb[t];
        }
    }
}

// final radix-4 stage of the 500-pt FFT (m=1, twiddles == 1)
template<bool INV>
__device__ __noinline__ void stage4(unsigned uoff, int lane){
    extern __shared__ char smem[];
    cplx* Uw = (cplx*)(smem + uoff);
#pragma unroll
    for(int it=0; it<2; ++it){
        int beta = lane + 64*it;
        if(beta < 125){
            int base = beta*4;
            cplx a[4];
#pragma unroll
            for(int t=0;t<4;++t) a[t] = Uw[PX(base+t)];
            cplx bb[4];
            dft4<INV>(a,bb);
#pragma unroll
            for(int t=0;t<4;++t) Uw[PX(base+t)] = bb[t];
        }
    }
}

// position p -> true k2 for the radix-(5,5,5,4) DIF order
__device__ __forceinline__ int p2k2(int p){
    int t1 = p/100; int r = p - 100*t1;
    int t2 = r/20;  r -= 20*t2;
    int t3 = r>>2;  int t4 = r & 3;
    return t1 + 5*t2 + 25*t3 + 125*t4;
}
// true k2 -> position p (inverse of p2k2)
__device__ __forceinline__ int k22p(int k){
    int t1 = k % 5; int k5 = k/5;
    int t2 = k5 % 5; int k25 = k5/5;
    int t3 = k25 % 5; int t4 = k25/5;
    return 100*t1 + 20*t2 + 4*t3 + t4;
}
// slot -> true k1.  Conjugate pairs (k1, 512-k1) in adjacent slots:
// slot 0,1 = {0, 256} (self-paired), slot 2j,2j+1 = {j, 512-j} for j>=1.
__device__ __forceinline__ int colord(int q){
    int j = q>>1, w = q&1;
    if(j == 0) return w ? 256 : 0;
    return w ? 512 - j : j;
}
// bijective XCD-chunk swizzle
__device__ __forceinline__ int xcd_chunk(int bid, int n){
    int q = n>>3, r = n&7;
    int x = bid&7, idx = bid>>3;
    return (x < r ? x*(q+1) : r*(q+1) + (x-r)*q) + idx;
}

// packed conjugate-pair filter
__device__ __forceinline__ void hpair(cplx Z1, cplx Z2, float ha, float hb,
                                      cplx* zk, cplx* znk){
    float xr = 0.5f*(Z1.x + Z2.x), xi = 0.5f*(Z1.y - Z2.y);   // Xa
    float yr = 0.5f*(Z1.y + Z2.y), yi = -0.5f*(Z1.x - Z2.x);  // Xb
    *zk  = make_float2(ha*xr - hb*yi, ha*xi + hb*yr);
    *znk = make_float2(ha*xr + hb*yi, hb*yr - ha*xi);
}

__device__ __forceinline__ void build_tab(cplx* tab, int tid, int ntab){
    const float step = -2.f*PI_F/(float)ntab;
    for(int i = tid; i < ntab; i += 256){
        float a = step*(float)i;
        tab[i] = make_float2(__cosf(a), __sinf(a));
    }
}

// ---------------------------------------------------------------------------
// ONE kernel image, launched 3x with phase = 0,1,2.  I$ stays warm across
// launches of the same code object; stage bodies appear once (noinline).
// Phase 0: packed fwd 512-FFT (+ frame-mean weights + logff table)
// Phase 1: per conjugate-pair: fwd 500-FFT, fused filter, inv 500-FFT
// Phase 2: inverse 512-FFT, unpack Re/Im -> 4 batches
// ---------------------------------------------------------------------------
__global__ void __launch_bounds__(256) kAll(const float* __restrict__ fm,
                                            const float* __restrict__ noise,
                                            float* __restrict__ out,
                                            cplx* __restrict__ Y,
                                            float* __restrict__ mmL,
                                            int phase){
    extern __shared__ char smem[];
    cplx* tab = (cplx*)smem;
    const int bid = blockIdx.x, tid = threadIdx.x;
    const int lane = tid & 63, w = tid >> 6;
    const unsigned uoffw = U_OFF + (unsigned)w*(UPAD*8u);
    cplx* Ucol0 = (cplx*)(smem + U_OFF);

    if(phase == 0){
        if(bid < 4){
            float* Aarr = (float*)(smem + EX_OFF);          // 500 f
            float* wfr  = (float*)(smem + EX_OFF + 2000);   // 500 f
            float* part = (float*)(smem + EX_OFF + 4000);   // 256 f
            const int b = bid;
            for(int f = tid; f < 500; f += 256){
                long long i0 = ((long long)f*255999LL + 498LL)/499LL;
                long long i1 = ((long long)(f+1)*255999LL + 498LL)/499LL;
                long long cnt = i1 - i0;
                long long sumi = (i0 + i1 - 1)*cnt/2;
                long long num = 499LL*sumi - cnt*(long long)f*255999LL;
                Aarr[f] = (float)((double)num / 255999.0);
            }
            __syncthreads();
            for(int f = tid; f < 500; f += 256){
                long long i0 = ((long long)f*255999LL + 498LL)/499LL;
                long long i1 = ((long long)(f+1)*255999LL + 498LL)/499LL;
                double ww;
                if(f < 499) ww = (double)(i1 - i0) - (double)Aarr[f] + (f > 0 ? (double)Aarr[f-1] : 0.0);
                else        ww = (double)Aarr[498] + 1.0;
                wfr[f] = (float)(ww / (double)NS);
            }
            __syncthreads();
            const int k = tid & 63, seg = tid >> 6;
            float acc = 0.f;
            for(int f = seg*125; f < seg*125 + 125; ++f)
                acc += wfr[f] * fm[(b*500 + f)*64 + k];
            part[seg*64 + k] = acc;
            __syncthreads();
            if(tid < 64) mmL[b*64 + tid] = part[tid] + part[64+tid] + part[128+tid] + part[192+tid];
            return;
        }
        if(bid == 4){
            if(tid < 64){
                // ff = 20 * (551.25)^(t/63); float math (rel err ~1e-6, tol 7.8e-3)
                float ff = __expf(2.99573227f + (float)tid*(6.31218815f/63.f));
                mmL[256 + tid] = __logf(ff + 1e-7f);
            }
            return;
        }
        // ---- packed forward 512-FFT: 4 columns per block ----
        const int g = xcd_chunk(bid - 5, 250);     // [0,250)
        const int s = g / 125;                     // signal
        const int n2base = (g - s*125) * 4;
        build_tab(tab, tid, 512);
        const float* xa = noise + (size_t)(2*s)*NS + n2base;
        const float* xb = noise + (size_t)(2*s+1)*NS + n2base;
#pragma unroll
        for(int k=0;k<8;++k){
            int i = tid + 256*k;                   // [0,2048)
            int n1 = i >> 2, ws = i & 3;
            (Ucol0 + ws*UPAD)[PX(n1)] = make_float2(xa[n1*500 + ws], xb[n1*500 + ws]);
        }
        __syncthreads();
        stage8<false>(uoffw, lane, 6); WFENCE();
        stage8<false>(uoffw, lane, 3); WFENCE();
        stage8<false>(uoffw, lane, 0); WFENCE();
        const int n2 = n2base + w;
        cplx* Uw = (cplx*)(smem + uoffw);
        cplx* yp = Y + ((size_t)s*500 + n2)*N1;
        const float tw = -2.f*PI_F/(float)NS;
#pragma unroll
        for(int t=0;t<8;++t){
            int q = lane + 64*t;
            int c = colord(q);
            cplx v = Uw[PX(rev8_3(c))];
            v = crotf(v, tw*(float)(n2*c));
            yp[q] = v;
        }
        return;
    }

    if(phase == 1){
        float* HrF = (float*)(smem + EX_OFF);           // [2][2][500]
        float* HrX = (float*)(smem + EX_OFF + 8000);    // [2][500]
        float* mmS = (float*)(smem + EX_OFF + 12000);   // [2][64]
        float* lgf = (float*)(smem + EX_OFF + 12512);   // [64]
        const int L = xcd_chunk(bid, 256);
        const int su = L >> 7;
        const int j0 = 2*(L & 127);           // first pair index (even)
        const int s0 = 2*j0;                  // first slot in Y
        cplx* Ybase = Y + (size_t)su*500*512 + s0;
        // issue the 4-column loads FIRST; in flight through tab/Hr compute
        cplx rg[8];
#pragma unroll
        for(int k=0;k<8;++k){
            int e = tid + 256*k;              // [0,2048) -> 2000 used
            rg[k] = (e < 2000) ? Ybase[(e>>2)*512 + (e&3)] : make_float2(0.f,0.f);
        }
        build_tab(tab, tid, 500);
        if(tid < 128) mmS[tid] = mmL[2*su*64 + tid];
        if(tid < 64)  lgf[tid] = mmL[256 + tid];
        LDS_BARRIER();                        // LDS visible; vmem NOT drained
        // filter response rows: r0 -> k1=j0, r1 -> j0+1, r2 -> 256 (special)
        const int special = (j0 == 0);
        const int nrows = special ? 3 : 2;
        const float invN = 1.f/(float)NS;
        for(int idx = tid; idx < nrows*500; idx += 256){
            int r = idx / 500;
            int p = idx - 500*r;
            int k1 = (r==0) ? j0 : ((r==1) ? j0+1 : 256);
            int k2 = p2k2(p);
            int kf = k1 + 512*k2;
            int kk = min(kf, NS - kf);
            float lf = __logf((float)kk*(22050.f/(float)NS) + 1e-7f);
            float wsum = 0.f, a0 = 0.f, a1 = 0.f;
#pragma unroll 8
            for(int jb=0;jb<64;++jb){
                float d = lf - lgf[jb];
                float e2 = __expf(-2.f*d*d);
                wsum += e2; a0 += e2*mmS[jb]; a1 += e2*mmS[64+jb];
            }
            float inv = invN/(wsum + 1e-7f);
            if(r < 2){ HrF[(r*2+0)*500 + p] = a0*inv; HrF[(r*2+1)*500 + p] = a1*inv; }
            else     { HrX[p] = a0*inv; HrX[500+p] = a1*inv; }
        }
        // park loads into LDS (compiler inserts the vmcnt waits here)
#pragma unroll
        for(int k=0;k<8;++k){
            int e = tid + 256*k;
            if(e < 2000) (Ucol0 + (e&3)*UPAD)[PX(e>>2)] = rg[k];
        }
        __syncthreads();
        stage5<false>(uoffw, lane, 100,   656u,  1); WFENCE();
        stage5<false>(uoffw, lane,  20,  3277u,  5); WFENCE();
        stage5<false>(uoffw, lane,   4, 16384u, 25); WFENCE();
        stage4<false>(uoffw, lane);
        __syncthreads();
        // ---- conjugate-pair unpack -> filter -> repack ----
        {
            const int u = w >> 1, cw = w & 1;
            cplx* UA = Ucol0 + (2*u)*UPAD;
            cplx* UB = Ucol0 + (2*u+1)*UPAD;
            if(special && u == 0){
                if(cw == 0){
                    // column k1=0, self-paired: partner k2' = (500-k2)%500
#pragma unroll 1
                    for(int t=0;t<8;++t){
                        int p = lane + 64*t;
                        if(p < 500){
                            int k2 = p2k2(p);
                            int pp = k22p((500 - k2) % 500);
                            if(p <= pp){
                                cplx Z1 = UA[PX(p)], Z2 = UA[PX(pp)];
                                cplx zk, znk;
                                hpair(Z1, Z2, HrF[p], HrF[500+p], &zk, &znk);
                                UA[PX(p)]  = zk;
                                UA[PX(pp)] = znk;
                            }
                        }
                    }
                } else {
                    // column k1=256, self-paired: partner position 499-p
#pragma unroll 1
                    for(int t=0;t<4;++t){
                        int p = lane + 64*t;
                        if(p < 250){
                            cplx Z1 = UB[PX(p)], Z2 = UB[PX(499-p)];
                            cplx zk, znk;
                            hpair(Z1, Z2, HrX[p], HrX[500+p], &zk, &znk);
                            UB[PX(p)]     = zk;
                            UB[PX(499-p)] = znk;
                        }
                    }
                }
            } else {
                // cross pair j=j0+u: (col k1=j, p) <-> (col 512-j, 499-p);
                // wave cw owns p in [cw*250, cw*250+250) -> disjoint writes.
                const float* H0 = HrF + (u*2+0)*500;
                const float* H1 = HrF + (u*2+1)*500;
#pragma unroll 1
                for(int t=0;t<4;++t){
                    int pl = lane + 64*t;
                    if(pl < 250){
                        int p = cw*250 + pl;
                        cplx Z1 = UA[PX(p)], Z2 = UB[PX(499-p)];
                        cplx zk, znk;
                        hpair(Z1, Z2, H0[p], H1[p], &zk, &znk);
                        UA[PX(p)]     = zk;
                        UB[PX(499-p)] = znk;
                    }
                }
            }
        }
        __syncthreads();
        stage4<true>(uoffw, lane); WFENCE();
        stage5<true>(uoffw, lane,   4, 16384u, 25); WFENCE();
        stage5<true>(uoffw, lane,  20,  3277u,  5); WFENCE();
        stage5<true>(uoffw, lane, 100,   656u,  1);
        __syncthreads();                      // store reads across all 4 columns
        const float tw2 = 2.f*PI_F/(float)NS;
#pragma unroll
        for(int k=0;k<8;++k){
            int e = tid + 256*k;
            if(e < 2000){
                int n2 = e >> 2, sl = e & 3;
                int cc = colord(s0 + sl);
                cplx v = (Ucol0 + sl*UPAD)[PX(n2)];
                v = crotf(v, tw2*(float)(n2*cc));
                Ybase[n2*512 + sl] = v;
            }
        }
        return;
    }

    // ---- phase 2: inverse 512-FFT, unpack ----
    {
        const int g = xcd_chunk(bid, 250);
        const int s = g / 125;
        const int n2base = (g - s*125) * 4;
        build_tab(tab, tid, 512);
        const cplx* yp = Y + ((size_t)s*500 + n2base)*N1;
#pragma unroll
        for(int k=0;k<8;++k){
            int i = tid + 256*k;                   // [0,2048)
            int ws = i >> 9, q = i & 511;          // coalesced in q
            cplx v = yp[(size_t)ws*N1 + q];
            (Ucol0 + ws*UPAD)[PX(rev8_3(colord(q)))] = v;
        }
        __syncthreads();
        stage8<true>(uoffw, lane, 0); WFENCE();
        stage8<true>(uoffw, lane, 3); WFENCE();
        stage8<true>(uoffw, lane, 6);
        __syncthreads();                           // store reads across columns
        float* oa = out + (size_t)(2*s)*NS + n2base;
        float* ob = out + (size_t)(2*s+1)*NS + n2base;
#pragma unroll
        for(int k=0;k<8;++k){
            int i = tid + 256*k;
            int n1 = i >> 2, ws = i & 3;
            cplx v = (Ucol0 + ws*UPAD)[PX(n1)];
            oa[n1*500 + ws] = v.x;
            ob[n1*500 + ws] = v.y;
        }
    }
}

// ---------------------------------------------------------------------------
extern "C" void kernel_launch(void* const* d_in, const int* in_sizes, int n_in,
                              void* d_out, int out_size, void* d_ws, size_t ws_size,
                              hipStream_t stream) {
    const float* fm = (const float*)d_in[0];     // (4,500,64)
    const float* noise = (const float*)d_in[1];  // (4,256000)
    float* out = (float*)d_out;

    char* ws = (char*)d_ws;
    cplx*  Y   = (cplx*)ws;                      // 2 signals * 500 * 512 cplx = 4,096,000 B
    float* mmL = (float*)(ws + 4194304);         // mm[4][64] + logff[64]

    kAll<<<255, 256, SMEM_BYTES, stream>>>(fm, noise, out, Y, mmL, 0);
    kAll<<<256, 256, SMEM_BYTES, stream>>>(fm, noise, out, Y, mmL, 1);
    kAll<<<250, 256, SMEM_BYTES, stream>>>(fm, noise, out, Y, mmL, 2);
}